// Round 2
// 820.578 us; speedup vs baseline: 1.0202x; 1.0202x over previous
//
#include <hip/hip_runtime.h>
#include <math.h>

// Problem constants (fixed by setup_inputs): B=2, S=65536, d=1024, csi=1023, k=7
#define D_MODEL   1024
#define SPLIT     64
#define B_BATCH   2
#define SEQ       65536
#define CSI       1023
#define NPREV     1023
#define KSEL      7
#define RCAND     32     // rescored candidates per batch (exact-fp32 safety net)

typedef __attribute__((ext_vector_type(8)))  short short8;
typedef __attribute__((ext_vector_type(16))) float floatx16;

static __device__ __forceinline__ ushort f2bf_rne(float x) {
    union { float f; unsigned u; } v; v.f = x;
    unsigned r = v.u + 0x7fffu + ((v.u >> 16) & 1u);
    return (ushort)(r >> 16);
}

// ============================================================================
// Kernel 1: bf16 MFMA scoring (hi-only). One block (256 thr / 4 waves) per
// (n, b). Each wave computes the FULL 64x64 sims tile for its k-quarter using
// 2x2 mfma_f32_32x32x16_bf16 tiles; partials reduced through LDS at the end.
//
// Plain bf16 (no hi/lo error-compensation split): the MFMA score only RANKS
// candidates; the top-RCAND are rescored in exact fp32 (kernel 3) before the
// top-7 cut, and bf16 score noise (~2e-4) is ~50x smaller than inter-candidate
// gaps at the rank-32 boundary. This cuts MFMA work 3x, conversion VALU 2x,
// and halves LDS (37.9 -> 19.4 KB/block) vs the hi/lo version.
//
// Row stride 72 bf16 (144B): fragment b128 reads hit all 32 banks (8-phase
// floor); staging writes are contiguous b64 (conflict-free).
// ============================================================================
#define RS  72
#define TSZ (SPLIT * RS)   // 4608 ushorts per tile

__global__ __launch_bounds__(256) void score_mfma(const float* __restrict__ emb,
                                                  float* __restrict__ scores) {
    const int n = blockIdx.x, b = blockIdx.y;
    const int t = threadIdx.x;
    const int lane = t & 63, wave = t >> 6;

    __shared__ ushort tiles[2 * TSZ];           // A | B (18.4 KB)
    __shared__ float sA[SPLIT], sB[SPLIT], ivA[SPLIT], ivB[SPLIT];
    ushort* At = tiles;
    ushort* Bt = tiles + TSZ;
    float* red = (float*)tiles;                 // epilogue reuse: 64 x 65 floats

    const float* curB = emb + ((size_t)b * SEQ + (size_t)CSI * SPLIT) * D_MODEL;
    const float* prvB = emb + ((size_t)b * SEQ + (size_t)n   * SPLIT) * D_MODEL;

    floatx16 acc[2][2] = {};
    float pA[4] = {0.f, 0.f, 0.f, 0.f}, pB[4] = {0.f, 0.f, 0.f, 0.f};

    // staging map: thread -> (row sr+16*it, cols sc..sc+3)
    const int sr = t >> 4;            // 0..15
    const int sc = (t & 15) << 2;     // 0..60

    // MFMA fragment LDS pointers (constant across chunks)
    const int rm  = lane & 31;
    const int kq  = (lane >> 5) << 3;       // 0 or 8
    const int kb  = wave << 4;              // wave's k-offset within chunk (k-split)
    const int fo  = rm * RS + kb + kq;
    const short8* fA0 = (const short8*)(At + fo);
    const short8* fA1 = (const short8*)(At + fo + 32 * RS);
    const short8* fB0 = (const short8*)(Bt + fo);
    const short8* fB1 = (const short8*)(Bt + fo + 32 * RS);

    for (int c = 0; c < 16; ++c) {
        const int k0 = c << 6;
        __syncthreads();   // previous chunk's fragment reads complete
        #pragma unroll
        for (int it = 0; it < 4; ++it) {
            const int r = sr + (it << 4);
            const float4 av = *(const float4*)(curB + (size_t)r * D_MODEL + k0 + sc);
            const float4 bv = *(const float4*)(prvB + (size_t)r * D_MODEL + k0 + sc);
            pA[it] = fmaf(av.x, av.x, fmaf(av.y, av.y, fmaf(av.z, av.z, fmaf(av.w, av.w, pA[it]))));
            pB[it] = fmaf(bv.x, bv.x, fmaf(bv.y, bv.y, fmaf(bv.z, bv.z, fmaf(bv.w, bv.w, pB[it]))));
            ushort4 h;
            h.x = f2bf_rne(av.x); h.y = f2bf_rne(av.y);
            h.z = f2bf_rne(av.z); h.w = f2bf_rne(av.w);
            *(ushort4*)(At + r * RS + sc) = h;
            h.x = f2bf_rne(bv.x); h.y = f2bf_rne(bv.y);
            h.z = f2bf_rne(bv.z); h.w = f2bf_rne(bv.w);
            *(ushort4*)(Bt + r * RS + sc) = h;
        }
        __syncthreads();

        const short8 a0 = *fA0, a1 = *fA1;
        const short8 b0 = *fB0, b1 = *fB1;

        acc[0][0] = __builtin_amdgcn_mfma_f32_32x32x16_bf16(a0, b0, acc[0][0], 0, 0, 0);
        acc[0][1] = __builtin_amdgcn_mfma_f32_32x32x16_bf16(a0, b1, acc[0][1], 0, 0, 0);
        acc[1][0] = __builtin_amdgcn_mfma_f32_32x32x16_bf16(a1, b0, acc[1][0], 0, 0, 0);
        acc[1][1] = __builtin_amdgcn_mfma_f32_32x32x16_bf16(a1, b1, acc[1][1], 0, 0, 0);
    }

    // ---- norms: reduce per-thread col-slice partials over 16 lanes ----
    #pragma unroll
    for (int m = 1; m < 16; m <<= 1) {
        #pragma unroll
        for (int it = 0; it < 4; ++it) {
            pA[it] += __shfl_xor(pA[it], m, 64);
            pB[it] += __shfl_xor(pB[it], m, 64);
        }
    }
    if ((t & 15) == 0) {
        #pragma unroll
        for (int it = 0; it < 4; ++it) { sA[sr + (it << 4)] = pA[it]; sB[sr + (it << 4)] = pB[it]; }
    }
    __syncthreads();   // norms ready; all tile reads done (red may overwrite tiles)
    if (t < 64)        ivB[t]      = 1.f / fmaxf(sqrtf(sB[t]),      1e-12f);
    else if (t < 128)  ivA[t - 64] = 1.f / fmaxf(sqrtf(sA[t - 64]), 1e-12f);
    __syncthreads();

    // ---- reduce 4 wave k-partials into red[64][65] ----
    const int cc = lane & 31;
    const int rquad = (lane >> 5) << 2;
    for (int ph = 0; ph < 4; ++ph) {
        if (wave == ph) {
            #pragma unroll
            for (int mt = 0; mt < 2; ++mt)
            #pragma unroll
            for (int nt = 0; nt < 2; ++nt) {
                #pragma unroll
                for (int r = 0; r < 16; ++r) {
                    const int row = mt * 32 + (r & 3) + ((r >> 2) << 3) + rquad;
                    const int col = nt * 32 + cc;
                    const float v = acc[mt][nt][r];
                    if (ph == 0) red[row * 65 + col] = v;
                    else         red[row * 65 + col] += v;
                }
            }
        }
        __syncthreads();
    }

    // ---- score = sum_q max_p sims ----
    if (t < 64) {
        const float* rr = red + t * 65;
        float m = -INFINITY;
        for (int p = 0; p < 64; ++p) m = fmaxf(m, rr[p] * ivB[p]);
        float v = m * ivA[t];
        #pragma unroll
        for (int o = 1; o < 64; o <<= 1) v += __shfl_xor(v, o, 64);
        if (t == 0) scores[(size_t)b * NPREV + n] = v;
    }
}

// ============================================================================
// Kernel 2: per batch, select top-RCAND candidate indices by MFMA score.
// ============================================================================
__global__ __launch_bounds__(256) void select_top(const float* __restrict__ scores,
                                                  int* __restrict__ sel) {
    const int b = blockIdx.x, t = threadIdx.x;
    __shared__ float sv[NPREV];
    __shared__ float wv[4]; __shared__ int wi[4];
    for (int i = t; i < NPREV; i += 256) sv[i] = scores[(size_t)b * NPREV + i];
    __syncthreads();
    for (int r = 0; r < RCAND; ++r) {
        float bv = -INFINITY; int bi = 0x7fffffff;
        for (int i = t; i < NPREV; i += 256) {
            const float v = sv[i];
            if (v > bv || (v == bv && i < bi)) { bv = v; bi = i; }
        }
        #pragma unroll
        for (int o = 1; o < 64; o <<= 1) {
            const float ov = __shfl_xor(bv, o, 64); const int oi = __shfl_xor(bi, o, 64);
            if (ov > bv || (ov == bv && oi < bi)) { bv = ov; bi = oi; }
        }
        if ((t & 63) == 0) { wv[t >> 6] = bv; wi[t >> 6] = bi; }
        __syncthreads();
        if (t == 0) {
            float fv = wv[0]; int fi = wi[0];
            for (int w = 1; w < 4; ++w)
                if (wv[w] > fv || (wv[w] == fv && wi[w] < fi)) { fv = wv[w]; fi = wi[w]; }
            sel[b * RCAND + r] = fi;
            sv[fi] = -INFINITY;
        }
        __syncthreads();
    }
}

// ============================================================================
// Kernel 3: exact-fp32 rescore of selected candidates (verbatim math)
// ============================================================================
#define BK      64
#define LDS_STR 68

__global__ __launch_bounds__(256) void rescore_kernel(const float* __restrict__ emb,
                                                      const int* __restrict__ sel,
                                                      float* __restrict__ resc) {
    const int j   = blockIdx.x;
    const int b   = blockIdx.y;
    const int n   = sel[b * RCAND + j];
    const int tid = threadIdx.x;
    const int tx  = tid & 15;
    const int ty  = tid >> 4;
    const int q0  = ty * 4;
    const int p0  = tx * 4;

    __shared__ float As[BK][LDS_STR];
    __shared__ float Bs[BK][LDS_STR];
    __shared__ float invA[SPLIT];
    __shared__ float invB[SPLIT];
    __shared__ float rowmax[SPLIT];

    const float* curBase = emb + ((size_t)b * SEQ + (size_t)CSI * SPLIT) * D_MODEL;
    const float* prvBase = emb + ((size_t)b * SEQ + (size_t)n   * SPLIT) * D_MODEL;

    float acc[4][4] = {};
    float ssq = 0.f;

    const int lr = tid >> 4;
    const int lc = (tid & 15) * 4;

    for (int k0 = 0; k0 < D_MODEL; k0 += BK) {
        __syncthreads();
        #pragma unroll
        for (int it = 0; it < 4; ++it) {
            const int r = lr + 16 * it;
            const float4 a  = *(const float4*)(curBase + (size_t)r * D_MODEL + k0 + lc);
            const float4 bv = *(const float4*)(prvBase + (size_t)r * D_MODEL + k0 + lc);
            As[lc + 0][r] = a.x;  As[lc + 1][r] = a.y;  As[lc + 2][r] = a.z;  As[lc + 3][r] = a.w;
            Bs[lc + 0][r] = bv.x; Bs[lc + 1][r] = bv.y; Bs[lc + 2][r] = bv.z; Bs[lc + 3][r] = bv.w;
        }
        __syncthreads();

        if (tid < 64) {
            const int p = tid;
            #pragma unroll 8
            for (int kk = 0; kk < BK; ++kk) { const float v = Bs[kk][p]; ssq = fmaf(v, v, ssq); }
        } else if (tid < 128) {
            const int q = tid - 64;
            #pragma unroll 8
            for (int kk = 0; kk < BK; ++kk) { const float v = As[kk][q]; ssq = fmaf(v, v, ssq); }
        }

        #pragma unroll 8
        for (int kk = 0; kk < BK; ++kk) {
            const float4 a  = *(const float4*)&As[kk][q0];
            const float4 bv = *(const float4*)&Bs[kk][p0];
            const float av[4]  = {a.x, a.y, a.z, a.w};
            const float bvv[4] = {bv.x, bv.y, bv.z, bv.w};
            #pragma unroll
            for (int i = 0; i < 4; ++i)
                #pragma unroll
                for (int jj = 0; jj < 4; ++jj)
                    acc[i][jj] = fmaf(av[i], bvv[jj], acc[i][jj]);
        }
    }

    __syncthreads();
    if (tid < 64)       invB[tid]      = 1.f / fmaxf(sqrtf(ssq), 1e-12f);
    else if (tid < 128) invA[tid - 64] = 1.f / fmaxf(sqrtf(ssq), 1e-12f);
    __syncthreads();

    float ibv[4];
    #pragma unroll
    for (int jj = 0; jj < 4; ++jj) ibv[jj] = invB[p0 + jj];

    float rmax[4];
    #pragma unroll
    for (int i = 0; i < 4; ++i) {
        float m = -INFINITY;
        #pragma unroll
        for (int jj = 0; jj < 4; ++jj) m = fmaxf(m, acc[i][jj] * ibv[jj]);
        rmax[i] = m * invA[q0 + i];
    }
    #pragma unroll
    for (int off = 1; off < 16; off <<= 1) {
        #pragma unroll
        for (int i = 0; i < 4; ++i)
            rmax[i] = fmaxf(rmax[i], __shfl_xor(rmax[i], off, 64));
    }
    if (tx == 0) {
        #pragma unroll
        for (int i = 0; i < 4; ++i) rowmax[q0 + i] = rmax[i];
    }
    __syncthreads();

    if (tid < 64) {
        float v = rowmax[tid];
        #pragma unroll
        for (int off = 1; off < 64; off <<= 1) v += __shfl_xor(v, off, 64);
        if (tid == 0) resc[b * RCAND + j] = v;
    }
}

// ============================================================================
// Kernel 4: top-7 of the RCAND exact scores, write outputs.
// Lanes 0..31 = batch 0, lanes 32..63 = batch 1 (xor-shuffles stay in-half).
// ============================================================================
__global__ void final_topk(const int* __restrict__ sel, const float* __restrict__ resc,
                           float* __restrict__ out) {
    const int t = threadIdx.x;            // 64 threads
    const int b = t >> 5, j = t & 31;
    float v  = resc[b * RCAND + j];
    const int idx = sel[b * RCAND + j];

    float outv = 0.f, maxv = 0.f; int outi = 0;
    for (int r = 0; r < KSEL; ++r) {
        float bv = v; int bi = idx;
        #pragma unroll
        for (int o = 1; o < 32; o <<= 1) {
            const float ov = __shfl_xor(bv, o, 64); const int oi = __shfl_xor(bi, o, 64);
            if (ov > bv || (ov == bv && oi < bi)) { bv = ov; bi = oi; }
        }
        if (r == 0) maxv = bv;
        if (j == r) { outv = bv; outi = bi; }
        if (idx == bi) v = -INFINITY;     // remove winner (indices unique)
    }
    if (j < KSEL) {
        out[b * (KSEL + 1) + j]                        = (float)outi;
        out[B_BATCH * (KSEL + 1) + b * (KSEL + 1) + j] = outv / (maxv + 1e-8f);
    }
    if (j == 31) {
        out[b * (KSEL + 1) + KSEL]                        = (float)CSI;
        out[B_BATCH * (KSEL + 1) + b * (KSEL + 1) + KSEL] = 1.0f;
    }
}

extern "C" void kernel_launch(void* const* d_in, const int* in_sizes, int n_in,
                              void* d_out, int out_size, void* d_ws, size_t ws_size,
                              hipStream_t stream) {
    const float* emb = (const float*)d_in[0];
    float* out = (float*)d_out;

    float* scores = (float*)d_ws;                              // 2046 floats
    int*   sel    = (int*)((char*)d_ws + 2048 * sizeof(float)); // 64 ints
    float* resc   = (float*)((char*)d_ws + 2048 * sizeof(float) + 64 * sizeof(int));

    dim3 g1(NPREV, B_BATCH);
    score_mfma<<<g1, 256, 0, stream>>>(emb, scores);
    select_top<<<B_BATCH, 256, 0, stream>>>(scores, sel);
    dim3 g3(RCAND, B_BATCH);
    rescore_kernel<<<g3, 256, 0, stream>>>(emb, sel, resc);
    final_topk<<<1, 64, 0, stream>>>(sel, resc, out);
}

// Round 3
// 810.964 us; speedup vs baseline: 1.0323x; 1.0119x over previous
//
#include <hip/hip_runtime.h>
#include <math.h>

// Problem constants (fixed by setup_inputs): B=2, S=65536, d=1024, csi=1023, k=7
#define D_MODEL   1024
#define SPLIT     64
#define B_BATCH   2
#define SEQ       65536
#define CSI       1023
#define NPREV     1023
#define KSEL      7
#define RCAND     32     // rescored candidates per batch (exact-fp32 safety net)

typedef __attribute__((ext_vector_type(8)))  short short8;
typedef __attribute__((ext_vector_type(16))) float floatx16;

static __device__ __forceinline__ ushort f2bf_rne(float x) {
    union { float f; unsigned u; } v; v.f = x;
    unsigned r = v.u + 0x7fffu + ((v.u >> 16) & 1u);
    return (ushort)(r >> 16);
}

// ============================================================================
// Kernel 0: one-shot cur-tile prep. Converts the (shared) cur split to bf16
// and computes its inverse L2 norms ONCE, instead of per-score-block (1023x).
// Grid: B_BATCH blocks x 256 thr; thread = (row, quarter-of-1024).
// ============================================================================
__global__ __launch_bounds__(256) void cvt_cur(const float* __restrict__ emb,
                                               ushort* __restrict__ curbf,
                                               float* __restrict__ curnorm) {
    const int b = blockIdx.x;
    const int t = threadIdx.x;
    const int row = t >> 2;          // 0..63
    const int q   = t & 3;           // 256-col quarter
    const float* src = emb + ((size_t)b * SEQ + (size_t)CSI * SPLIT + row) * D_MODEL + q * 256;
    ushort* dst = curbf + ((size_t)b * SPLIT + row) * D_MODEL + q * 256;
    float ssq = 0.f;
    #pragma unroll 8
    for (int i = 0; i < 64; ++i) {
        const float4 v = *(const float4*)(src + i * 4);
        ssq = fmaf(v.x, v.x, fmaf(v.y, v.y, fmaf(v.z, v.z, fmaf(v.w, v.w, ssq))));
        ushort4 h;
        h.x = f2bf_rne(v.x); h.y = f2bf_rne(v.y);
        h.z = f2bf_rne(v.z); h.w = f2bf_rne(v.w);
        *(ushort4*)(dst + i * 4) = h;
    }
    // rows occupy 4 consecutive lanes -> reduce quarters with xor 1,2
    ssq += __shfl_xor(ssq, 1, 64);
    ssq += __shfl_xor(ssq, 2, 64);
    if (q == 0) curnorm[b * SPLIT + row] = 1.f / fmaxf(sqrtf(ssq), 1e-12f);
}

// ============================================================================
// Kernel 1: bf16 MFMA scoring (hi-only). One block (256 thr / 4 waves) per
// (n, b). Each wave computes the FULL 64x64 sims tile for its k-quarter using
// 2x2 mfma_f32_32x32x16_bf16 tiles; partials reduced through LDS at the end.
// cur arrives pre-converted (kernel 0): staging it is a pure ushort4 copy,
// and its norms are read from curnorm — roughly halves the staging VALU.
// Score only RANKS candidates; exact fp32 rescore (kernel 3) fixes outputs.
// Row stride 72 bf16 (144B): fragment b128 reads hit all 32 banks.
// ============================================================================
#define RS  72
#define TSZ (SPLIT * RS)   // 4608 ushorts per tile

__global__ __launch_bounds__(256) void score_mfma(const float* __restrict__ emb,
                                                  const ushort* __restrict__ curbf,
                                                  const float* __restrict__ curnorm,
                                                  float* __restrict__ scores) {
    const int n = blockIdx.x, b = blockIdx.y;
    const int t = threadIdx.x;
    const int lane = t & 63, wave = t >> 6;

    __shared__ ushort tiles[2 * TSZ];           // A | B (18.4 KB)
    __shared__ float sB[SPLIT], ivB[SPLIT];
    ushort* At = tiles;
    ushort* Bt = tiles + TSZ;
    float* red = (float*)tiles;                 // epilogue reuse: 64 x 65 floats

    const ushort* curA = curbf + (size_t)b * SPLIT * D_MODEL;
    const float*  prvB = emb + ((size_t)b * SEQ + (size_t)n * SPLIT) * D_MODEL;

    floatx16 acc[2][2] = {};
    float pB[4] = {0.f, 0.f, 0.f, 0.f};

    // staging map: thread -> (row sr+16*it, cols sc..sc+3)
    const int sr = t >> 4;            // 0..15
    const int sc = (t & 15) << 2;     // 0..60

    // MFMA fragment LDS pointers (constant across chunks)
    const int rm  = lane & 31;
    const int kq  = (lane >> 5) << 3;       // 0 or 8
    const int kb  = wave << 4;              // wave's k-offset within chunk (k-split)
    const int fo  = rm * RS + kb + kq;
    const short8* fA0 = (const short8*)(At + fo);
    const short8* fA1 = (const short8*)(At + fo + 32 * RS);
    const short8* fB0 = (const short8*)(Bt + fo);
    const short8* fB1 = (const short8*)(Bt + fo + 32 * RS);

    for (int c = 0; c < 16; ++c) {
        const int k0 = c << 6;
        __syncthreads();   // previous chunk's fragment reads complete
        #pragma unroll
        for (int it = 0; it < 4; ++it) {
            const int r = sr + (it << 4);
            // A: pre-converted bf16, straight copy to LDS
            *(ushort4*)(At + r * RS + sc) =
                *(const ushort4*)(curA + (size_t)r * D_MODEL + k0 + sc);
            // B: fp32 load, norm partial, convert
            const float4 bv = *(const float4*)(prvB + (size_t)r * D_MODEL + k0 + sc);
            pB[it] = fmaf(bv.x, bv.x, fmaf(bv.y, bv.y, fmaf(bv.z, bv.z, fmaf(bv.w, bv.w, pB[it]))));
            ushort4 h;
            h.x = f2bf_rne(bv.x); h.y = f2bf_rne(bv.y);
            h.z = f2bf_rne(bv.z); h.w = f2bf_rne(bv.w);
            *(ushort4*)(Bt + r * RS + sc) = h;
        }
        __syncthreads();

        const short8 a0 = *fA0, a1 = *fA1;
        const short8 b0 = *fB0, b1 = *fB1;

        acc[0][0] = __builtin_amdgcn_mfma_f32_32x32x16_bf16(a0, b0, acc[0][0], 0, 0, 0);
        acc[0][1] = __builtin_amdgcn_mfma_f32_32x32x16_bf16(a0, b1, acc[0][1], 0, 0, 0);
        acc[1][0] = __builtin_amdgcn_mfma_f32_32x32x16_bf16(a1, b0, acc[1][0], 0, 0, 0);
        acc[1][1] = __builtin_amdgcn_mfma_f32_32x32x16_bf16(a1, b1, acc[1][1], 0, 0, 0);
    }

    // ---- B norms: reduce per-thread col-slice partials over 16 lanes ----
    #pragma unroll
    for (int m = 1; m < 16; m <<= 1) {
        #pragma unroll
        for (int it = 0; it < 4; ++it) pB[it] += __shfl_xor(pB[it], m, 64);
    }
    if ((t & 15) == 0) {
        #pragma unroll
        for (int it = 0; it < 4; ++it) sB[sr + (it << 4)] = pB[it];
    }
    __syncthreads();   // norms ready; all tile reads done (red may overwrite tiles)
    if (t < 64) ivB[t] = 1.f / fmaxf(sqrtf(sB[t]), 1e-12f);
    __syncthreads();

    // ---- reduce 4 wave k-partials into red[64][65] ----
    const int cc = lane & 31;
    const int rquad = (lane >> 5) << 2;
    for (int ph = 0; ph < 4; ++ph) {
        if (wave == ph) {
            #pragma unroll
            for (int mt = 0; mt < 2; ++mt)
            #pragma unroll
            for (int nt = 0; nt < 2; ++nt) {
                #pragma unroll
                for (int r = 0; r < 16; ++r) {
                    const int row = mt * 32 + (r & 3) + ((r >> 2) << 3) + rquad;
                    const int col = nt * 32 + cc;
                    const float v = acc[mt][nt][r];
                    if (ph == 0) red[row * 65 + col] = v;
                    else         red[row * 65 + col] += v;
                }
            }
        }
        __syncthreads();
    }

    // ---- score = sum_q max_p sims ----
    if (t < 64) {
        const float myIvA = curnorm[b * SPLIT + t];
        const float* rr = red + t * 65;
        float m = -INFINITY;
        for (int p = 0; p < 64; ++p) m = fmaxf(m, rr[p] * ivB[p]);
        float v = m * myIvA;
        #pragma unroll
        for (int o = 1; o < 64; o <<= 1) v += __shfl_xor(v, o, 64);
        if (t == 0) scores[(size_t)b * NPREV + n] = v;
    }
}

// ============================================================================
// Kernel 2: per batch, select top-RCAND candidate indices by MFMA score.
// Single wave per batch, fully in-register: lane holds 16 scores (stride-64
// layout), 32 rounds of unrolled local-max + 6-step shuffle reduce. No LDS,
// no barriers (the old version paid 64 block barriers on a 2-block grid).
// All v[] accesses are in fully-unrolled loops -> static register indices.
// ============================================================================
__global__ void select_top(const float* __restrict__ scores,
                           int* __restrict__ sel) {
    const int t = threadIdx.x;            // 128 threads: wave 0 = b0, wave 1 = b1
    const int b = t >> 6, lane = t & 63;
    float v[16];
    #pragma unroll
    for (int i = 0; i < 16; ++i) {
        const int idx = lane + (i << 6);
        v[i] = (idx < NPREV) ? scores[(size_t)b * NPREV + idx] : -INFINITY;
    }
    for (int r = 0; r < RCAND; ++r) {
        float bv = -INFINITY; int bi = 0x7fffffff;
        #pragma unroll
        for (int i = 0; i < 16; ++i) {
            const int idx = lane + (i << 6);
            if (v[i] > bv) { bv = v[i]; bi = idx; }   // ascending idx: strict > keeps lowest
        }
        #pragma unroll
        for (int o = 1; o < 64; o <<= 1) {
            const float ov = __shfl_xor(bv, o, 64);
            const int   oi = __shfl_xor(bi, o, 64);
            if (ov > bv || (ov == bv && oi < bi)) { bv = ov; bi = oi; }
        }
        if (lane == 0) sel[b * RCAND + r] = bi;
        #pragma unroll
        for (int i = 0; i < 16; ++i)
            if (bi == lane + (i << 6)) v[i] = -INFINITY;   // remove winner
    }
}

// ============================================================================
// Kernel 3: exact-fp32 rescore of selected candidates (verbatim math)
// ============================================================================
#define BK      64
#define LDS_STR 68

__global__ __launch_bounds__(256) void rescore_kernel(const float* __restrict__ emb,
                                                      const int* __restrict__ sel,
                                                      float* __restrict__ resc) {
    const int j   = blockIdx.x;
    const int b   = blockIdx.y;
    const int n   = sel[b * RCAND + j];
    const int tid = threadIdx.x;
    const int tx  = tid & 15;
    const int ty  = tid >> 4;
    const int q0  = ty * 4;
    const int p0  = tx * 4;

    __shared__ float As[BK][LDS_STR];
    __shared__ float Bs[BK][LDS_STR];
    __shared__ float invA[SPLIT];
    __shared__ float invB[SPLIT];
    __shared__ float rowmax[SPLIT];

    const float* curBase = emb + ((size_t)b * SEQ + (size_t)CSI * SPLIT) * D_MODEL;
    const float* prvBase = emb + ((size_t)b * SEQ + (size_t)n   * SPLIT) * D_MODEL;

    float acc[4][4] = {};
    float ssq = 0.f;

    const int lr = tid >> 4;
    const int lc = (tid & 15) * 4;

    for (int k0 = 0; k0 < D_MODEL; k0 += BK) {
        __syncthreads();
        #pragma unroll
        for (int it = 0; it < 4; ++it) {
            const int r = lr + 16 * it;
            const float4 a  = *(const float4*)(curBase + (size_t)r * D_MODEL + k0 + lc);
            const float4 bv = *(const float4*)(prvBase + (size_t)r * D_MODEL + k0 + lc);
            As[lc + 0][r] = a.x;  As[lc + 1][r] = a.y;  As[lc + 2][r] = a.z;  As[lc + 3][r] = a.w;
            Bs[lc + 0][r] = bv.x; Bs[lc + 1][r] = bv.y; Bs[lc + 2][r] = bv.z; Bs[lc + 3][r] = bv.w;
        }
        __syncthreads();

        if (tid < 64) {
            const int p = tid;
            #pragma unroll 8
            for (int kk = 0; kk < BK; ++kk) { const float v = Bs[kk][p]; ssq = fmaf(v, v, ssq); }
        } else if (tid < 128) {
            const int q = tid - 64;
            #pragma unroll 8
            for (int kk = 0; kk < BK; ++kk) { const float v = As[kk][q]; ssq = fmaf(v, v, ssq); }
        }

        #pragma unroll 8
        for (int kk = 0; kk < BK; ++kk) {
            const float4 a  = *(const float4*)&As[kk][q0];
            const float4 bv = *(const float4*)&Bs[kk][p0];
            const float av[4]  = {a.x, a.y, a.z, a.w};
            const float bvv[4] = {bv.x, bv.y, bv.z, bv.w};
            #pragma unroll
            for (int i = 0; i < 4; ++i)
                #pragma unroll
                for (int jj = 0; jj < 4; ++jj)
                    acc[i][jj] = fmaf(av[i], bvv[jj], acc[i][jj]);
        }
    }

    __syncthreads();
    if (tid < 64)       invB[tid]      = 1.f / fmaxf(sqrtf(ssq), 1e-12f);
    else if (tid < 128) invA[tid - 64] = 1.f / fmaxf(sqrtf(ssq), 1e-12f);
    __syncthreads();

    float ibv[4];
    #pragma unroll
    for (int jj = 0; jj < 4; ++jj) ibv[jj] = invB[p0 + jj];

    float rmax[4];
    #pragma unroll
    for (int i = 0; i < 4; ++i) {
        float m = -INFINITY;
        #pragma unroll
        for (int jj = 0; jj < 4; ++jj) m = fmaxf(m, acc[i][jj] * ibv[jj]);
        rmax[i] = m * invA[q0 + i];
    }
    #pragma unroll
    for (int off = 1; off < 16; off <<= 1) {
        #pragma unroll
        for (int i = 0; i < 4; ++i)
            rmax[i] = fmaxf(rmax[i], __shfl_xor(rmax[i], off, 64));
    }
    if (tx == 0) {
        #pragma unroll
        for (int i = 0; i < 4; ++i) rowmax[q0 + i] = rmax[i];
    }
    __syncthreads();

    if (tid < 64) {
        float v = rowmax[tid];
        #pragma unroll
        for (int off = 1; off < 64; off <<= 1) v += __shfl_xor(v, off, 64);
        if (tid == 0) resc[b * RCAND + j] = v;
    }
}

// ============================================================================
// Kernel 4: top-7 of the RCAND exact scores, write outputs.
// Lanes 0..31 = batch 0, lanes 32..63 = batch 1 (xor-shuffles stay in-half).
// ============================================================================
__global__ void final_topk(const int* __restrict__ sel, const float* __restrict__ resc,
                           float* __restrict__ out) {
    const int t = threadIdx.x;            // 64 threads
    const int b = t >> 5, j = t & 31;
    float v  = resc[b * RCAND + j];
    const int idx = sel[b * RCAND + j];

    float outv = 0.f, maxv = 0.f; int outi = 0;
    for (int r = 0; r < KSEL; ++r) {
        float bv = v; int bi = idx;
        #pragma unroll
        for (int o = 1; o < 32; o <<= 1) {
            const float ov = __shfl_xor(bv, o, 64); const int oi = __shfl_xor(bi, o, 64);
            if (ov > bv || (ov == bv && oi < bi)) { bv = ov; bi = oi; }
        }
        if (r == 0) maxv = bv;
        if (j == r) { outv = bv; outi = bi; }
        if (idx == bi) v = -INFINITY;     // remove winner (indices unique)
    }
    if (j < KSEL) {
        out[b * (KSEL + 1) + j]                        = (float)outi;
        out[B_BATCH * (KSEL + 1) + b * (KSEL + 1) + j] = outv / (maxv + 1e-8f);
    }
    if (j == 31) {
        out[b * (KSEL + 1) + KSEL]                        = (float)CSI;
        out[B_BATCH * (KSEL + 1) + b * (KSEL + 1) + KSEL] = 1.0f;
    }
}

extern "C" void kernel_launch(void* const* d_in, const int* in_sizes, int n_in,
                              void* d_out, int out_size, void* d_ws, size_t ws_size,
                              hipStream_t stream) {
    const float* emb = (const float*)d_in[0];
    float* out = (float*)d_out;

    // workspace layout (all rewritten every launch before use):
    //   [0, 16K)    scores (2046 floats)
    //   [16K, 17K)  sel    (64 ints)
    //   [17K, 18K)  resc   (64 floats)
    //   [18K, 19K)  curnorm (128 floats)
    //   [20K, +256K) curbf  (2 x 64 x 1024 ushort)
    char* ws = (char*)d_ws;
    float*  scores  = (float*)ws;
    int*    sel     = (int*)(ws + (16 << 10));
    float*  resc    = (float*)(ws + (17 << 10));
    float*  curnorm = (float*)(ws + (18 << 10));
    ushort* curbf   = (ushort*)(ws + (20 << 10));

    cvt_cur<<<B_BATCH, 256, 0, stream>>>(emb, curbf, curnorm);
    dim3 g1(NPREV, B_BATCH);
    score_mfma<<<g1, 256, 0, stream>>>(emb, curbf, curnorm, scores);
    select_top<<<1, 128, 0, stream>>>(scores, sel);
    dim3 g3(RCAND, B_BATCH);
    rescore_kernel<<<g3, 256, 0, stream>>>(emb, sel, resc);
    final_topk<<<1, 64, 0, stream>>>(sel, resc, out);
}